// Round 16
// baseline (877.548 us; speedup 1.0000x reference)
//
#include <hip/hip_runtime.h>

#define HIDN 128
#define VSTR 272           // LDS V-buffer row stride BYTES (17x16B -> conflict-free b128)
#define ASTR 132           // f32 activation row stride (floats)

// d_ws byte offsets — weight rows padded to non-power-of-2 byte strides (R14 win).
#define WSB_W2F 0                    // f32 [128] rows, stride 528B
#define WSB_W3F 67584
#define WSB_W2B 135168               // bf16 [128] rows, stride 272B
#define WSB_W3B 169984
#define WSB_W4B 204800               // bf16 [16] rows, stride 272B (rows 4..15 zero)
#define WSB_W1T 209152               // bf16 [4][128] contiguous
#define WSB_TOT 210176

typedef __attribute__((ext_vector_type(8))) short short8;
typedef __attribute__((ext_vector_type(4))) float f32x4;

// ---- forward W pipeline: issue-only batch of 8 rows (528B apart), uniform addr ----
#define FWD_ISSUE8(dst, base)                                                 \
    asm volatile("global_load_dwordx4 %0, %8, off\n\t"                        \
                 "global_load_dwordx4 %1, %8, off offset:528\n\t"             \
                 "global_load_dwordx4 %2, %8, off offset:1056\n\t"            \
                 "global_load_dwordx4 %3, %8, off offset:1584\n\t"            \
                 "global_load_dwordx4 %4, %8, off offset:2112\n\t"            \
                 "global_load_dwordx4 %5, %8, off offset:2640\n\t"            \
                 "global_load_dwordx4 %6, %8, off offset:3168\n\t"            \
                 "global_load_dwordx4 %7, %8, off offset:3696"                \
                 : "=&v"(dst[0]), "=&v"(dst[1]), "=&v"(dst[2]), "=&v"(dst[3]),\
                   "=&v"(dst[4]), "=&v"(dst[5]), "=&v"(dst[6]), "=&v"(dst[7]) \
                 : "v"(base))

// Wait until group g complete; g's regs as "+v" so dependent FMAs stay after.
#define FWD_WAIT(n, g)                                                        \
    asm volatile("s_waitcnt vmcnt(" #n ")"                                    \
                 : "+v"(g[0]), "+v"(g[1]), "+v"(g[2]), "+v"(g[3]),            \
                   "+v"(g[4]), "+v"(g[5]), "+v"(g[6]), "+v"(g[7]))

// Batched 4-slice bf16 W load (short8 each), slices 64B apart within a 272B row.
#define LOAD_A4(dst, base)                                                    \
    asm volatile("global_load_dwordx4 %0, %4, off\n\t"                        \
                 "global_load_dwordx4 %1, %4, off offset:64\n\t"              \
                 "global_load_dwordx4 %2, %4, off offset:128\n\t"             \
                 "global_load_dwordx4 %3, %4, off offset:192\n\t"             \
                 "s_waitcnt vmcnt(0)"                                         \
                 : "=&v"(dst[0]), "=&v"(dst[1]), "=&v"(dst[2]), "=&v"(dst[3]) \
                 : "v"(base)                                                  \
                 : "memory")

// f32 -> bf16 round-to-nearest-even
__device__ __forceinline__ unsigned short f2bf(float f) {
    unsigned b = __float_as_uint(f);
    b += 0x7FFFu + ((b >> 16) & 1u);
    return (unsigned short)(b >> 16);
}

// ---------- prelude: one-time weight repack (padded strides) into ws ----------
__global__ void conv_w_kernel(const float* __restrict__ W1, const float* __restrict__ W2,
                              const float* __restrict__ W3, const float* __restrict__ W4,
                              unsigned char* __restrict__ ws)
{
    const int idx = blockIdx.x * 256 + threadIdx.x;
    if (idx < 16384) {
        const int r = idx >> 7, c = idx & 127;
        *(float*)(ws + WSB_W2F + r * 528 + c * 4) = W2[idx];          // f32 verbatim (bit-exact)
        *(float*)(ws + WSB_W3F + r * 528 + c * 4) = W3[idx];
        *(unsigned short*)(ws + WSB_W2B + r * 272 + c * 2) = f2bf(W2[idx]);
        *(unsigned short*)(ws + WSB_W3B + r * 272 + c * 2) = f2bf(W3[idx]);
    } else if (idx < 16384 + 2048) {
        const int t = idx - 16384;
        const int r = t >> 7, c = t & 127;
        *(unsigned short*)(ws + WSB_W4B + r * 272 + c * 2) =
            (r < 4) ? f2bf(W4[r * HIDN + c]) : (unsigned short)0;
    } else if (idx < 16384 + 2048 + 512) {
        const int t = idx - 16384 - 2048;
        const int cc = t >> 7, j = t & 127;
        *(unsigned short*)(ws + WSB_W1T + cc * 256 + j * 2) = f2bf(W1[j * 4 + cc]);
    }
}

// One tangent layer, PING-PONG (src != dst; in-place corrupts — R6/R8, 2-for-2).
// Wave owns V rows [wv*16, wv*16+16). A = W rows (bf16, 272B-padded), B = V cols.
// R7/R9/R13/R14/R15-proven, byte-identical to R15.
__device__ __forceinline__ void tangent_layer(const unsigned char* __restrict__ src,
                                              unsigned char* __restrict__ dst,
                                              const unsigned char* __restrict__ Wb, // 272B rows
                                              const unsigned char* __restrict__ msk, // [16][16]
                                              int wv, int lr, int lk)
{
    short8 b[4];
    #pragma unroll
    for (int ks = 0; ks < 4; ++ks)
        b[ks] = *(const short8*)(src + (wv * 16 + lr) * VSTR + ks * 64 + lk * 16);

    const int sc = wv * 16 + lr;
    #pragma unroll
    for (int ib = 0; ib < 8; ++ib) {
        short8 a[4];
        LOAD_A4(a, Wb + (ib * 16 + lr) * 272 + lk * 16);
        f32x4 c = (f32x4){0.f, 0.f, 0.f, 0.f};
        #pragma unroll
        for (int ks = 0; ks < 4; ++ks)
            c = __builtin_amdgcn_mfma_f32_16x16x32_bf16(a[ks], b[ks], c, 0, 0, 0);
        const unsigned bits = (msk[(sc >> 2) * 16 + ib * 2 + (lk >> 1)] >> ((lk & 1) * 4)) & 0xFu;
        unsigned long long pk = 0;
        #pragma unroll
        for (int r = 0; r < 4; ++r) {
            const unsigned short v = ((bits >> r) & 1u) ? f2bf(c[r]) : (unsigned short)0;
            pk |= (unsigned long long)v << (r * 16);
        }
        *(unsigned long long*)(dst + sc * VSTR + ib * 32 + lk * 8) = pk;
    }
}

__global__ __launch_bounds__(256, 4)
void wnn_jac_kernel(const float* __restrict__ u,
                    const float* __restrict__ W1, const float* __restrict__ b1,
                    const float* __restrict__ b2, const float* __restrict__ b3,
                    const unsigned char* __restrict__ wsb,
                    float* __restrict__ out, int Btot)
{
    // [0,17408) vA ; [17408,34816) vB ; forward aliases [0,33792) as f32 abuf[64][132]
    __shared__ __align__(16) unsigned char smem[34816];
    __shared__ unsigned char mlds8[3][64][16];   // [layer][sample][unit>>3] (3072 B)
    __shared__ float jbuf[64 * 5];               // [sc][c'] stride 5 (1280 B)

    unsigned char* vA = smem;
    unsigned char* vB = smem + 17408;
    float* abuf = (float*)smem;

    const int tid  = threadIdx.x;
    const long sg0 = (long)blockIdx.x * 64;

    // ================== FORWARD: lane = sample, wave = unit-quarter (uniform W) ==================
    {
        const int ls = tid & 63;                                   // sample
        const int wq = __builtin_amdgcn_readfirstlane(tid >> 6);   // uniform quarter 0..3
        const int i0 = wq * 32;
        const bool valid = (sg0 + ls < (long)Btot);

        float4 uv = make_float4(0.f, 0.f, 0.f, 0.f);
        if (valid) uv = *(const float4*)(u + (sg0 + ls) * 4);

        // ---- layer 1: 32 units/wave (uniform W1 rows), bit-exact chain, bias after ----
        {
            unsigned m = 0;
            #pragma unroll
            for (int ii = 0; ii < 32; ++ii) {
                const int i = i0 + ii;
                const float4 w = *(const float4*)(W1 + i * 4);     // uniform
                float h = 0.f;
                h = fmaf(w.x, uv.x, h);
                h = fmaf(w.y, uv.y, h);
                h = fmaf(w.z, uv.z, h);
                h = fmaf(w.w, uv.w, h);
                h = h + b1[i];
                if (h > 0.f) m |= (1u << ii);
                abuf[ls * ASTR + i] = fmaxf(h, 0.f);
            }
            *(unsigned*)&mlds8[0][ls][wq * 4] = m;
        }
        __syncthreads();   // B1: a1 complete

        // ---- pipelined f32 matvec pass: 8 units, depth-3 W prefetch, bit-exact chain ----
        // acc[e] accumulates jc ascending, x/y/z/w — identical arithmetic to R15.
        float acc2[32];

        #define FWD_STEP(jc, WB)                                              \
        {                                                                     \
            if ((jc) < 30) { FWD_WAIT(16, WB); }                              \
            else if ((jc) == 30) { FWD_WAIT(8, WB); }                         \
            else { FWD_WAIT(0, WB); }                                         \
            const f32x4 av = *(const f32x4*)(abuf + ls * ASTR + (jc) * 4);    \
            _Pragma("unroll")                                                 \
            for (int e = 0; e < 8; ++e) {                                     \
                float a = acc[e];                                             \
                a = fmaf(WB[e][0], av[0], a);                                 \
                a = fmaf(WB[e][1], av[1], a);                                 \
                a = fmaf(WB[e][2], av[2], a);                                 \
                a = fmaf(WB[e][3], av[3], a);                                 \
                acc[e] = a;                                                   \
            }                                                                 \
            if ((jc) + 3 < 32) FWD_ISSUE8(WB, wp + ((jc) + 3) * 16);          \
        }
        #define FWD_STEP3(j) FWD_STEP(j, w0) FWD_STEP((j)+1, w1) FWD_STEP((j)+2, w2)
        #define FWD_PASS(WSOFF, u8)                                           \
        {                                                                     \
            const unsigned char* wp = wsb + (WSOFF) + (i0 + (u8) * 8) * 528;  \
            f32x4 w0[8], w1[8], w2[8];                                        \
            FWD_ISSUE8(w0, wp);                                               \
            FWD_ISSUE8(w1, wp + 16);                                          \
            FWD_ISSUE8(w2, wp + 32);                                          \
            float acc[8];                                                     \
            _Pragma("unroll")                                                 \
            for (int e = 0; e < 8; ++e) acc[e] = 0.f;                         \
            FWD_STEP3(0)  FWD_STEP3(3)  FWD_STEP3(6)  FWD_STEP3(9)            \
            FWD_STEP3(12) FWD_STEP3(15) FWD_STEP3(18) FWD_STEP3(21)           \
            FWD_STEP3(24) FWD_STEP3(27) FWD_STEP(30, w0) FWD_STEP(31, w1)     \
            _Pragma("unroll")                                                 \
            for (int e = 0; e < 8; ++e) acc2[(u8) * 8 + e] = acc[e];          \
        }

        // ---- layer 2 ----
        FWD_PASS(WSB_W2F, 0)
        FWD_PASS(WSB_W2F, 1)
        FWD_PASS(WSB_W2F, 2)
        FWD_PASS(WSB_W2F, 3)
        __syncthreads();   // B2: ALL a1 reads complete -> safe to overwrite abuf with a2
        {
            unsigned m = 0;
            #pragma unroll
            for (int ii = 0; ii < 32; ++ii) {
                const float h = acc2[ii] + b2[i0 + ii];
                if (h > 0.f) m |= (1u << ii);
                abuf[ls * ASTR + i0 + ii] = fmaxf(h, 0.f);
            }
            *(unsigned*)&mlds8[1][ls][wq * 4] = m;
        }
        __syncthreads();   // B3: a2 complete

        // ---- layer 3 (mask only) ----
        FWD_PASS(WSB_W3F, 0)
        FWD_PASS(WSB_W3F, 1)
        FWD_PASS(WSB_W3F, 2)
        FWD_PASS(WSB_W3F, 3)
        {
            unsigned m = 0;
            #pragma unroll
            for (int ii = 0; ii < 32; ++ii) {
                const float h = acc2[ii] + b3[i0 + ii];
                if (h > 0.f) m |= (1u << ii);
            }
            *(unsigned*)&mlds8[2][ls][wq * 4] = m;
        }
    }

    // ================== TANGENT: 4 subtiles of 16 samples (R15-identical) ==================
    const unsigned char* ml8 = &mlds8[0][0][0];
    const int lane = tid & 63, wv = tid >> 6;
    const int lr = lane & 15, lk = lane >> 4;

    #pragma unroll 1
    for (int st = 0; st < 4; ++st) {
        __syncthreads();   // 1st iter: masks visible + abuf dead; later: jbuf/vA reuse safe

        // ---- v1 build: vA row sc=s_local*4+c = bf16(m1[sample][j] * W1[j][c]) ----
        {
            const int row = tid >> 2, kq = tid & 3;
            const int vs = row >> 2, vc = row & 3;
            const unsigned char* mrec = ml8 + (0 * 64 + st * 16 + vs) * 16;
            const unsigned short* w1t = (const unsigned short*)(wsb + WSB_W1T) + vc * HIDN;
            #pragma unroll
            for (int t = 0; t < 4; ++t) {
                const int j0 = kq * 32 + t * 8;
                const short8 w = *(const short8*)(w1t + j0);
                short8 fr;
                #pragma unroll
                for (int e = 0; e < 8; ++e) {
                    const int j = j0 + e;
                    fr[e] = ((mrec[j >> 3] >> (j & 7)) & 1u) ? w[e] : (short)0;
                }
                *(short8*)(vA + row * VSTR + j0 * 2) = fr;
            }
        }

        // ---- tangent layers 2,3 (ping-pong vA -> vB -> vA; wave-private rows) ----
        tangent_layer(vA, vB, wsb + WSB_W2B, ml8 + (1 * 64 + st * 16) * 16, wv, lr, lk);
        tangent_layer(vB, vA, wsb + WSB_W3B, ml8 + (2 * 64 + st * 16) * 16, wv, lr, lk);

        // ---- Jf: D[c'][sc] = sum_j W4[c'][j] * V3[sc][j] ----
        {
            short8 a4f[4], b[4];
            #pragma unroll
            for (int ks = 0; ks < 4; ++ks) {
                a4f[ks] = *(const short8*)(wsb + WSB_W4B + lr * 272 + ks * 64 + lk * 16);
                b[ks]   = *(const short8*)(vA + (wv * 16 + lr) * VSTR + ks * 64 + lk * 16);
            }
            f32x4 c = (f32x4){0.f, 0.f, 0.f, 0.f};
            #pragma unroll
            for (int ks = 0; ks < 4; ++ks)
                c = __builtin_amdgcn_mfma_f32_16x16x32_bf16(a4f[ks], b[ks], c, 0, 0, 0);
            if (lk == 0) {
                const int sc = wv * 16 + lr;
                #pragma unroll
                for (int r = 0; r < 4; ++r)
                    jbuf[sc * 5 + r] = c[r];
            }
        }
        __syncthreads();   // jbuf complete

        // ---- epilogue: out[s][a][b'] = Jf[b'][a] - Jf[a][b'] ----
        if (tid < 64) {
            const int es = tid >> 2, ea = tid & 3;
            const long sg = sg0 + st * 16 + es;
            if (sg < (long)Btot) {
                float4 o;
                o.x = jbuf[(es * 4 + ea) * 5 + 0] - jbuf[(es * 4 + 0) * 5 + ea];
                o.y = jbuf[(es * 4 + ea) * 5 + 1] - jbuf[(es * 4 + 1) * 5 + ea];
                o.z = jbuf[(es * 4 + ea) * 5 + 2] - jbuf[(es * 4 + 2) * 5 + ea];
                o.w = jbuf[(es * 4 + ea) * 5 + 3] - jbuf[(es * 4 + 3) * 5 + ea];
                *(float4*)(out + sg * 16 + ea * 4) = o;
            }
        }
    }
}

extern "C" void kernel_launch(void* const* d_in, const int* in_sizes, int n_in,
                              void* d_out, int out_size, void* d_ws, size_t ws_size,
                              hipStream_t stream)
{
    const float* u  = (const float*)d_in[0];
    const float* W1 = (const float*)d_in[1];
    const float* b1 = (const float*)d_in[2];
    const float* W2 = (const float*)d_in[3];
    const float* b2 = (const float*)d_in[4];
    const float* W3 = (const float*)d_in[5];
    const float* b3 = (const float*)d_in[6];
    const float* W4 = (const float*)d_in[7];
    // d_in[8] = b4: unused (bias does not enter the Jacobian)
    float* out = (float*)d_out;
    unsigned char* wsb = (unsigned char*)d_ws;   // needs 210176 B

    const int B = in_sizes[0] / 4;
    hipLaunchKernelGGL(conv_w_kernel, dim3((16384 + 2048 + 512 + 255) / 256), dim3(256), 0, stream,
                       W1, W2, W3, W4, wsb);
    const int nblocks = (B + 63) / 64;
    hipLaunchKernelGGL(wnn_jac_kernel, dim3(nblocks), dim3(256), 0, stream,
                       u, W1, b1, b2, b3, wsb, out, B);
}

// Round 18
// 333.768 us; speedup vs baseline: 2.6292x; 2.6292x over previous
//
#include <hip/hip_runtime.h>

#define HIDN 128
#define VSTR 272           // LDS V-buffer row stride BYTES (17x16B -> conflict-free b128)
#define ASTR 132           // f32 activation row stride (floats)

// d_ws byte offsets — weight rows padded to non-power-of-2 byte strides (R14 win).
#define WSB_W2F 0                    // f32 [128] rows, stride 528B
#define WSB_W3F 67584
#define WSB_W2B 135168               // bf16 [128] rows, stride 272B
#define WSB_W3B 169984
#define WSB_W4B 204800               // bf16 [16] rows, stride 272B (rows 4..15 zero)
#define WSB_W1T 209152               // bf16 [4][128] contiguous
#define WSB_TOT 210176

typedef __attribute__((ext_vector_type(8))) short short8;
typedef __attribute__((ext_vector_type(4))) float f32x4;

// Paired-ib bf16 W load: 8 loads (two 272B rows, 4 slices each) + wait in ONE
// self-contained asm block (R13-proven pattern; multi-block pipelines spill — R16).
#define LOAD_A8(dst, b0, b1)                                                  \
    asm volatile("global_load_dwordx4 %0, %8, off\n\t"                        \
                 "global_load_dwordx4 %1, %8, off offset:64\n\t"              \
                 "global_load_dwordx4 %2, %8, off offset:128\n\t"             \
                 "global_load_dwordx4 %3, %8, off offset:192\n\t"             \
                 "global_load_dwordx4 %4, %9, off\n\t"                        \
                 "global_load_dwordx4 %5, %9, off offset:64\n\t"              \
                 "global_load_dwordx4 %6, %9, off offset:128\n\t"             \
                 "global_load_dwordx4 %7, %9, off offset:192\n\t"             \
                 "s_waitcnt vmcnt(0)"                                         \
                 : "=&v"(dst[0]), "=&v"(dst[1]), "=&v"(dst[2]), "=&v"(dst[3]),\
                   "=&v"(dst[4]), "=&v"(dst[5]), "=&v"(dst[6]), "=&v"(dst[7]) \
                 : "v"(b0), "v"(b1)                                           \
                 : "memory")

// f32 -> bf16 round-to-nearest-even
__device__ __forceinline__ unsigned short f2bf(float f) {
    unsigned b = __float_as_uint(f);
    b += 0x7FFFu + ((b >> 16) & 1u);
    return (unsigned short)(b >> 16);
}

// ---------- prelude: one-time weight repack (padded strides) into ws ----------
__global__ void conv_w_kernel(const float* __restrict__ W1, const float* __restrict__ W2,
                              const float* __restrict__ W3, const float* __restrict__ W4,
                              unsigned char* __restrict__ ws)
{
    const int idx = blockIdx.x * 256 + threadIdx.x;
    if (idx < 16384) {
        const int r = idx >> 7, c = idx & 127;
        *(float*)(ws + WSB_W2F + r * 528 + c * 4) = W2[idx];          // f32 verbatim (bit-exact)
        *(float*)(ws + WSB_W3F + r * 528 + c * 4) = W3[idx];
        *(unsigned short*)(ws + WSB_W2B + r * 272 + c * 2) = f2bf(W2[idx]);
        *(unsigned short*)(ws + WSB_W3B + r * 272 + c * 2) = f2bf(W3[idx]);
    } else if (idx < 16384 + 2048) {
        const int t = idx - 16384;
        const int r = t >> 7, c = t & 127;
        *(unsigned short*)(ws + WSB_W4B + r * 272 + c * 2) =
            (r < 4) ? f2bf(W4[r * HIDN + c]) : (unsigned short)0;
    } else if (idx < 16384 + 2048 + 512) {
        const int t = idx - 16384 - 2048;
        const int cc = t >> 7, j = t & 127;
        *(unsigned short*)(ws + WSB_W1T + cc * 256 + j * 2) = f2bf(W1[j * 4 + cc]);
    }
}

// One tangent layer, PING-PONG (src != dst; in-place corrupts — R6/R8, 2-for-2).
// Wave owns V rows [wv*16, wv*16+16) — fully wave-private, no barriers needed.
// msk = SUBTILE SAMPLE BASE [16][16]; this function adds the wave offset via sc>>2.
// (R17 bug: caller added wv*4 into the base too -> waves 1-3 read wrong masks.)
__device__ __forceinline__ void tangent_layer(const unsigned char* __restrict__ src,
                                              unsigned char* __restrict__ dst,
                                              const unsigned char* __restrict__ Wb, // 272B rows
                                              const unsigned char* __restrict__ msk, // [16][16]
                                              int wv, int lr, int lk)
{
    short8 b[4];
    #pragma unroll
    for (int ks = 0; ks < 4; ++ks)
        b[ks] = *(const short8*)(src + (wv * 16 + lr) * VSTR + ks * 64 + lk * 16);

    const int sc = wv * 16 + lr;
    #pragma unroll
    for (int ip = 0; ip < 4; ++ip) {
        short8 a[8];
        LOAD_A8(a, Wb + ((ip * 2 + 0) * 16 + lr) * 272 + lk * 16,
                   Wb + ((ip * 2 + 1) * 16 + lr) * 272 + lk * 16);
        #pragma unroll
        for (int h = 0; h < 2; ++h) {
            const int ib = ip * 2 + h;
            f32x4 c = (f32x4){0.f, 0.f, 0.f, 0.f};
            #pragma unroll
            for (int ks = 0; ks < 4; ++ks)
                c = __builtin_amdgcn_mfma_f32_16x16x32_bf16(a[h * 4 + ks], b[ks], c, 0, 0, 0);
            const unsigned bits = (msk[(sc >> 2) * 16 + ib * 2 + (lk >> 1)] >> ((lk & 1) * 4)) & 0xFu;
            unsigned long long pk = 0;
            #pragma unroll
            for (int r = 0; r < 4; ++r) {
                const unsigned short v = ((bits >> r) & 1u) ? f2bf(c[r]) : (unsigned short)0;
                pk |= (unsigned long long)v << (r * 16);
            }
            *(unsigned long long*)(dst + sc * VSTR + ib * 32 + lk * 8) = pk;
        }
    }
}

__global__ __launch_bounds__(256, 4)
void wnn_jac_kernel(const float* __restrict__ u,
                    const float* __restrict__ W1, const float* __restrict__ b1,
                    const float* __restrict__ b2, const float* __restrict__ b3,
                    const unsigned char* __restrict__ wsb,
                    float* __restrict__ out, int Btot)
{
    // [0,17408) vA ; [17408,34816) vB ; forward aliases [0,33792) as f32 abuf[64][132]
    __shared__ __align__(16) unsigned char smem[34816];
    __shared__ unsigned char mlds8[3][64][16];   // [layer][sample][unit>>3] (3072 B)
    __shared__ float jbuf[64 * 5];               // [sc][c'] stride 5 (1280 B)

    unsigned char* vA = smem;
    unsigned char* vB = smem + 17408;
    float* abuf = (float*)smem;

    const int tid  = threadIdx.x;
    const long sg0 = (long)blockIdx.x * 64;

    // ================== FORWARD: lane = sample, wave = unit-quarter (uniform W) — R15 verbatim ==================
    {
        const int ls = tid & 63;                                   // sample
        const int wq = __builtin_amdgcn_readfirstlane(tid >> 6);   // uniform quarter 0..3
        const int i0 = wq * 32;
        const bool valid = (sg0 + ls < (long)Btot);

        float4 uv = make_float4(0.f, 0.f, 0.f, 0.f);
        if (valid) uv = *(const float4*)(u + (sg0 + ls) * 4);

        // ---- layer 1: 32 units/wave (uniform W1 rows), bit-exact chain, bias after ----
        {
            unsigned m = 0;
            #pragma unroll
            for (int ii = 0; ii < 32; ++ii) {
                const int i = i0 + ii;
                const float4 w = *(const float4*)(W1 + i * 4);     // uniform
                float h = 0.f;
                h = fmaf(w.x, uv.x, h);
                h = fmaf(w.y, uv.y, h);
                h = fmaf(w.z, uv.z, h);
                h = fmaf(w.w, uv.w, h);
                h = h + b1[i];
                if (h > 0.f) m |= (1u << ii);
                abuf[ls * ASTR + i] = fmaxf(h, 0.f);
            }
            *(unsigned*)&mlds8[0][ls][wq * 4] = m;
        }
        __syncthreads();   // B1: a1 complete

        // ---- layer 2: uniform W rows (scalar path), lane-local activations from LDS ----
        float acc2[32];
        {
            #pragma unroll
            for (int u8 = 0; u8 < 4; ++u8) {
                float acc[8];
                #pragma unroll
                for (int e = 0; e < 8; ++e) acc[e] = 0.f;
                #pragma unroll 4
                for (int jc = 0; jc < 32; ++jc) {
                    const f32x4 av = *(const f32x4*)(abuf + ls * ASTR + jc * 4);
                    #pragma unroll
                    for (int e = 0; e < 8; ++e) {
                        const float* wr = (const float*)(wsb + WSB_W2F
                                              + (i0 + u8 * 8 + e) * 528 + jc * 16); // uniform
                        float a = acc[e];
                        a = fmaf(wr[0], av[0], a);
                        a = fmaf(wr[1], av[1], a);
                        a = fmaf(wr[2], av[2], a);
                        a = fmaf(wr[3], av[3], a);
                        acc[e] = a;
                    }
                }
                #pragma unroll
                for (int e = 0; e < 8; ++e) acc2[u8 * 8 + e] = acc[e];
            }
        }
        __syncthreads();   // B2: ALL a1 reads complete -> safe to overwrite abuf with a2
        {
            unsigned m = 0;
            #pragma unroll
            for (int ii = 0; ii < 32; ++ii) {
                const float h = acc2[ii] + b2[i0 + ii];
                if (h > 0.f) m |= (1u << ii);
                abuf[ls * ASTR + i0 + ii] = fmaxf(h, 0.f);
            }
            *(unsigned*)&mlds8[1][ls][wq * 4] = m;
        }
        __syncthreads();   // B3: a2 complete

        // ---- layer 3 (mask only) ----
        {
            #pragma unroll
            for (int u8 = 0; u8 < 4; ++u8) {
                float acc[8];
                #pragma unroll
                for (int e = 0; e < 8; ++e) acc[e] = 0.f;
                #pragma unroll 4
                for (int jc = 0; jc < 32; ++jc) {
                    const f32x4 av = *(const f32x4*)(abuf + ls * ASTR + jc * 4);
                    #pragma unroll
                    for (int e = 0; e < 8; ++e) {
                        const float* wr = (const float*)(wsb + WSB_W3F
                                              + (i0 + u8 * 8 + e) * 528 + jc * 16); // uniform
                        float a = acc[e];
                        a = fmaf(wr[0], av[0], a);
                        a = fmaf(wr[1], av[1], a);
                        a = fmaf(wr[2], av[2], a);
                        a = fmaf(wr[3], av[3], a);
                        acc[e] = a;
                    }
                }
                #pragma unroll
                for (int e = 0; e < 8; ++e) acc2[u8 * 8 + e] = acc[e];
            }
            unsigned m = 0;
            #pragma unroll
            for (int ii = 0; ii < 32; ++ii) {
                const float h = acc2[ii] + b3[i0 + ii];
                if (h > 0.f) m |= (1u << ii);
            }
            *(unsigned*)&mlds8[2][ls][wq * 4] = m;
        }
    }
    __syncthreads();   // B4 — the ONLY barrier before the tangent phase: masks visible,
                       // all abuf reads done. Everything below is wave-private.

    // ================== TANGENT: 4 subtiles, ZERO barriers (wave-private rows) ==================
    const unsigned char* ml8 = &mlds8[0][0][0];
    const int lane = tid & 63, wv = tid >> 6;
    const int lr = lane & 15, lk = lane >> 4;

    #pragma unroll 1
    for (int st = 0; st < 4; ++st) {
        // ---- v1 build: vA rows [wv*16, wv*16+16) = bf16(m1 .* W1 cols) — wave-private ----
        {
            const int row = wv * 16 + (lane >> 2), kq = lane & 3;
            const int vs = (lane >> 4), vc = (lane >> 2) & 3;
            const unsigned char* mrec = ml8 + (0 * 64 + st * 16 + wv * 4 + vs) * 16;
            const unsigned short* w1t = (const unsigned short*)(wsb + WSB_W1T) + vc * HIDN;
            #pragma unroll
            for (int t = 0; t < 4; ++t) {
                const int j0 = kq * 32 + t * 8;
                const short8 w = *(const short8*)(w1t + j0);
                short8 fr;
                #pragma unroll
                for (int e = 0; e < 8; ++e) {
                    const int j = j0 + e;
                    fr[e] = ((mrec[j >> 3] >> (j & 7)) & 1u) ? w[e] : (short)0;
                }
                *(short8*)(vA + row * VSTR + j0 * 2) = fr;
            }
        }

        // ---- tangent layers 2,3 (ping-pong vA -> vB -> vA; wave-private rows) ----
        // Mask arg = subtile sample base; tangent_layer adds the wave offset (sc>>2).
        tangent_layer(vA, vB, wsb + WSB_W2B, ml8 + (1 * 64 + st * 16) * 16, wv, lr, lk);
        tangent_layer(vB, vA, wsb + WSB_W3B, ml8 + (2 * 64 + st * 16) * 16, wv, lr, lk);

        // ---- Jf: D[c'][sc] = sum_j W4[c'][j] * V3[sc][j] ----
        {
            short8 a4f[4], b[4];
            #pragma unroll
            for (int ks = 0; ks < 4; ++ks) {
                a4f[ks] = *(const short8*)(wsb + WSB_W4B + lr * 272 + ks * 64 + lk * 16);
                b[ks]   = *(const short8*)(vA + (wv * 16 + lr) * VSTR + ks * 64 + lk * 16);
            }
            f32x4 c = (f32x4){0.f, 0.f, 0.f, 0.f};
            #pragma unroll
            for (int ks = 0; ks < 4; ++ks)
                c = __builtin_amdgcn_mfma_f32_16x16x32_bf16(a4f[ks], b[ks], c, 0, 0, 0);
            if (lk == 0) {   // c' = r (0..3); sc = wv*16+lr  -> jbuf rows wave-private
                const int sc = wv * 16 + lr;
                #pragma unroll
                for (int r = 0; r < 4; ++r)
                    jbuf[sc * 5 + r] = c[r];
            }
        }
        // wave-internal jbuf handoff: both sides are LDS ops -> "memory" clobber orders them
        asm volatile("s_waitcnt lgkmcnt(0)" ::: "memory");
        __builtin_amdgcn_sched_barrier(0);

        // ---- per-wave epilogue (lanes 0-15): samples wv*4 .. wv*4+3 of this subtile ----
        if (lk == 0) {
            const int es = lr >> 2, ea = lr & 3;          // sample-in-wave, output row
            const long sg = sg0 + st * 16 + wv * 4 + es;
            if (sg < (long)Btot) {
                const float* jb = jbuf + (wv * 16 + es * 4) * 5;
                float4 o;
                o.x = jb[ea * 5 + 0] - jb[0 * 5 + ea];
                o.y = jb[ea * 5 + 1] - jb[1 * 5 + ea];
                o.z = jb[ea * 5 + 2] - jb[2 * 5 + ea];
                o.w = jb[ea * 5 + 3] - jb[3 * 5 + ea];
                *(float4*)(out + sg * 16 + ea * 4) = o;
            }
        }
    }
}

extern "C" void kernel_launch(void* const* d_in, const int* in_sizes, int n_in,
                              void* d_out, int out_size, void* d_ws, size_t ws_size,
                              hipStream_t stream)
{
    const float* u  = (const float*)d_in[0];
    const float* W1 = (const float*)d_in[1];
    const float* b1 = (const float*)d_in[2];
    const float* W2 = (const float*)d_in[3];
    const float* b2 = (const float*)d_in[4];
    const float* W3 = (const float*)d_in[5];
    const float* b3 = (const float*)d_in[6];
    const float* W4 = (const float*)d_in[7];
    // d_in[8] = b4: unused (bias does not enter the Jacobian)
    float* out = (float*)d_out;
    unsigned char* wsb = (unsigned char*)d_ws;   // needs 210176 B

    const int B = in_sizes[0] / 4;
    hipLaunchKernelGGL(conv_w_kernel, dim3((16384 + 2048 + 512 + 255) / 256), dim3(256), 0, stream,
                       W1, W2, W3, W4, wsb);
    const int nblocks = (B + 63) / 64;
    hipLaunchKernelGGL(wnn_jac_kernel, dim3(nblocks), dim3(256), 0, stream,
                       u, W1, b1, b2, b3, wsb, out, B);
}

// Round 19
// 319.472 us; speedup vs baseline: 2.7469x; 1.0447x over previous
//
#include <hip/hip_runtime.h>

#define HIDN 128
#define VSTR 272           // LDS V-buffer row stride BYTES (17x16B -> conflict-free b128)
#define ASTR 132           // f32 activation row stride (floats)

// d_ws byte offsets. Forward weights TRANSPOSED: WT[jc][unit][4kk] f32, row
// stride 2064B (2048+16 pad, non-pow2 — R14). Per jc-step the 8 needed units
// are 128B CONTIGUOUS -> 2 cache lines (vs 8 with row-major) on the scalar path.
#define WSB_W2T 0                    // f32 [32][128][4], rows 2064B
#define WSB_W3T 66048
#define WSB_W2B 135168               // bf16 [128] rows, stride 272B (tangent)
#define WSB_W3B 169984
#define WSB_W4B 204800               // bf16 [16] rows, stride 272B (rows 4..15 zero)
#define WSB_W1T 209152               // bf16 [4][128] contiguous
#define WSB_TOT 210176

typedef __attribute__((ext_vector_type(8))) short short8;
typedef __attribute__((ext_vector_type(4))) float f32x4;

// Paired-ib bf16 W load: 8 loads + wait in ONE self-contained asm block
// (R13-proven; multi-block register pipelines spill — R16, 3-for-3).
#define LOAD_A8(dst, b0, b1)                                                  \
    asm volatile("global_load_dwordx4 %0, %8, off\n\t"                        \
                 "global_load_dwordx4 %1, %8, off offset:64\n\t"              \
                 "global_load_dwordx4 %2, %8, off offset:128\n\t"             \
                 "global_load_dwordx4 %3, %8, off offset:192\n\t"             \
                 "global_load_dwordx4 %4, %9, off\n\t"                        \
                 "global_load_dwordx4 %5, %9, off offset:64\n\t"              \
                 "global_load_dwordx4 %6, %9, off offset:128\n\t"             \
                 "global_load_dwordx4 %7, %9, off offset:192\n\t"             \
                 "s_waitcnt vmcnt(0)"                                         \
                 : "=&v"(dst[0]), "=&v"(dst[1]), "=&v"(dst[2]), "=&v"(dst[3]),\
                   "=&v"(dst[4]), "=&v"(dst[5]), "=&v"(dst[6]), "=&v"(dst[7]) \
                 : "v"(b0), "v"(b1)                                           \
                 : "memory")

// f32 -> bf16 round-to-nearest-even
__device__ __forceinline__ unsigned short f2bf(float f) {
    unsigned b = __float_as_uint(f);
    b += 0x7FFFu + ((b >> 16) & 1u);
    return (unsigned short)(b >> 16);
}

// ---------- prelude: one-time weight repack into ws ----------
__global__ void conv_w_kernel(const float* __restrict__ W1, const float* __restrict__ W2,
                              const float* __restrict__ W3, const float* __restrict__ W4,
                              unsigned char* __restrict__ ws)
{
    const int idx = blockIdx.x * 256 + threadIdx.x;
    if (idx < 16384) {
        const int r = idx >> 7, c = idx & 127;           // unit r, k-col c
        const int jc = c >> 2, kk = c & 3;
        *(float*)(ws + WSB_W2T + jc * 2064 + r * 16 + kk * 4) = W2[idx];   // f32 verbatim
        *(float*)(ws + WSB_W3T + jc * 2064 + r * 16 + kk * 4) = W3[idx];
        *(unsigned short*)(ws + WSB_W2B + r * 272 + c * 2) = f2bf(W2[idx]);
        *(unsigned short*)(ws + WSB_W3B + r * 272 + c * 2) = f2bf(W3[idx]);
    } else if (idx < 16384 + 2048) {
        const int t = idx - 16384;
        const int r = t >> 7, c = t & 127;
        *(unsigned short*)(ws + WSB_W4B + r * 272 + c * 2) =
            (r < 4) ? f2bf(W4[r * HIDN + c]) : (unsigned short)0;
    } else if (idx < 16384 + 2048 + 512) {
        const int t = idx - 16384 - 2048;
        const int cc = t >> 7, j = t & 127;
        *(unsigned short*)(ws + WSB_W1T + cc * 256 + j * 2) = f2bf(W1[j * 4 + cc]);
    }
}

// One tangent layer, PING-PONG (src != dst; in-place corrupts — R6/R8, 2-for-2).
// Wave owns V rows [wv*16, wv*16+16) — wave-private, no barriers.
// msk = SUBTILE SAMPLE BASE [16][16]; wave offset added here via sc>>2 (R17 lesson).
__device__ __forceinline__ void tangent_layer(const unsigned char* __restrict__ src,
                                              unsigned char* __restrict__ dst,
                                              const unsigned char* __restrict__ Wb, // 272B rows
                                              const unsigned char* __restrict__ msk, // [16][16]
                                              int wv, int lr, int lk)
{
    short8 b[4];
    #pragma unroll
    for (int ks = 0; ks < 4; ++ks)
        b[ks] = *(const short8*)(src + (wv * 16 + lr) * VSTR + ks * 64 + lk * 16);

    const int sc = wv * 16 + lr;
    #pragma unroll
    for (int ip = 0; ip < 4; ++ip) {
        short8 a[8];
        LOAD_A8(a, Wb + ((ip * 2 + 0) * 16 + lr) * 272 + lk * 16,
                   Wb + ((ip * 2 + 1) * 16 + lr) * 272 + lk * 16);
        #pragma unroll
        for (int h = 0; h < 2; ++h) {
            const int ib = ip * 2 + h;
            f32x4 c = (f32x4){0.f, 0.f, 0.f, 0.f};
            #pragma unroll
            for (int ks = 0; ks < 4; ++ks)
                c = __builtin_amdgcn_mfma_f32_16x16x32_bf16(a[h * 4 + ks], b[ks], c, 0, 0, 0);
            const unsigned bits = (msk[(sc >> 2) * 16 + ib * 2 + (lk >> 1)] >> ((lk & 1) * 4)) & 0xFu;
            unsigned long long pk = 0;
            #pragma unroll
            for (int r = 0; r < 4; ++r) {
                const unsigned short v = ((bits >> r) & 1u) ? f2bf(c[r]) : (unsigned short)0;
                pk |= (unsigned long long)v << (r * 16);
            }
            *(unsigned long long*)(dst + sc * VSTR + ib * 32 + lk * 8) = pk;
        }
    }
}

__global__ __launch_bounds__(256, 4)
void wnn_jac_kernel(const float* __restrict__ u,
                    const float* __restrict__ W1, const float* __restrict__ b1,
                    const float* __restrict__ b2, const float* __restrict__ b3,
                    const unsigned char* __restrict__ wsb,
                    float* __restrict__ out, int Btot)
{
    // [0,17408) vA ; [17408,34816) vB ; forward aliases [0,33792) as f32 abuf[64][132]
    __shared__ __align__(16) unsigned char smem[34816];
    __shared__ unsigned char mlds8[3][64][16];   // [layer][sample][unit>>3] (3072 B)
    __shared__ float jbuf[64 * 5];               // [sc][c'] stride 5 (1280 B)

    unsigned char* vA = smem;
    unsigned char* vB = smem + 17408;
    float* abuf = (float*)smem;

    const int tid  = threadIdx.x;
    const long sg0 = (long)blockIdx.x * 64;

    // ================== FORWARD: lane = sample, wave = unit-quarter (uniform W) ==================
    {
        const int ls = tid & 63;                                   // sample
        const int wq = __builtin_amdgcn_readfirstlane(tid >> 6);   // uniform quarter 0..3
        const int i0 = wq * 32;
        const bool valid = (sg0 + ls < (long)Btot);

        float4 uv = make_float4(0.f, 0.f, 0.f, 0.f);
        if (valid) uv = *(const float4*)(u + (sg0 + ls) * 4);

        // ---- layer 1: 32 units/wave (uniform W1 rows), bit-exact chain, bias after ----
        {
            unsigned m = 0;
            #pragma unroll
            for (int ii = 0; ii < 32; ++ii) {
                const int i = i0 + ii;
                const float4 w = *(const float4*)(W1 + i * 4);     // uniform
                float h = 0.f;
                h = fmaf(w.x, uv.x, h);
                h = fmaf(w.y, uv.y, h);
                h = fmaf(w.z, uv.z, h);
                h = fmaf(w.w, uv.w, h);
                h = h + b1[i];
                if (h > 0.f) m |= (1u << ii);
                abuf[ls * ASTR + i] = fmaxf(h, 0.f);
            }
            *(unsigned*)&mlds8[0][ls][wq * 4] = m;
        }
        __syncthreads();   // B1: a1 complete

        // ---- layer 2: transposed W (contiguous 128B per jc-step), bit-exact chain ----
        float acc2[32];
        {
            #pragma unroll
            for (int u8 = 0; u8 < 4; ++u8) {
                float acc[8];
                #pragma unroll
                for (int e = 0; e < 8; ++e) acc[e] = 0.f;
                #pragma unroll 8
                for (int jc = 0; jc < 32; ++jc) {
                    const f32x4 av = *(const f32x4*)(abuf + ls * ASTR + jc * 4);
                    const float* wt = (const float*)(wsb + WSB_W2T + jc * 2064
                                                     + (i0 + u8 * 8) * 16);   // uniform, 128B
                    #pragma unroll
                    for (int e = 0; e < 8; ++e) {
                        const float* wr = wt + e * 4;
                        float a = acc[e];
                        a = fmaf(wr[0], av[0], a);
                        a = fmaf(wr[1], av[1], a);
                        a = fmaf(wr[2], av[2], a);
                        a = fmaf(wr[3], av[3], a);
                        acc[e] = a;
                    }
                }
                #pragma unroll
                for (int e = 0; e < 8; ++e) acc2[u8 * 8 + e] = acc[e];
            }
        }
        __syncthreads();   // B2: ALL a1 reads complete -> safe to overwrite abuf with a2
        {
            unsigned m = 0;
            #pragma unroll
            for (int ii = 0; ii < 32; ++ii) {
                const float h = acc2[ii] + b2[i0 + ii];
                if (h > 0.f) m |= (1u << ii);
                abuf[ls * ASTR + i0 + ii] = fmaxf(h, 0.f);
            }
            *(unsigned*)&mlds8[1][ls][wq * 4] = m;
        }
        __syncthreads();   // B3: a2 complete

        // ---- layer 3 (mask only) ----
        {
            #pragma unroll
            for (int u8 = 0; u8 < 4; ++u8) {
                float acc[8];
                #pragma unroll
                for (int e = 0; e < 8; ++e) acc[e] = 0.f;
                #pragma unroll 8
                for (int jc = 0; jc < 32; ++jc) {
                    const f32x4 av = *(const f32x4*)(abuf + ls * ASTR + jc * 4);
                    const float* wt = (const float*)(wsb + WSB_W3T + jc * 2064
                                                     + (i0 + u8 * 8) * 16);   // uniform, 128B
                    #pragma unroll
                    for (int e = 0; e < 8; ++e) {
                        const float* wr = wt + e * 4;
                        float a = acc[e];
                        a = fmaf(wr[0], av[0], a);
                        a = fmaf(wr[1], av[1], a);
                        a = fmaf(wr[2], av[2], a);
                        a = fmaf(wr[3], av[3], a);
                        acc[e] = a;
                    }
                }
                #pragma unroll
                for (int e = 0; e < 8; ++e) acc2[u8 * 8 + e] = acc[e];
            }
            unsigned m = 0;
            #pragma unroll
            for (int ii = 0; ii < 32; ++ii) {
                const float h = acc2[ii] + b3[i0 + ii];
                if (h > 0.f) m |= (1u << ii);
            }
            *(unsigned*)&mlds8[2][ls][wq * 4] = m;
        }
    }
    __syncthreads();   // B4 — the ONLY barrier before the tangent phase.

    // ================== TANGENT: 4 subtiles, ZERO barriers (wave-private rows) ==================
    const unsigned char* ml8 = &mlds8[0][0][0];
    const int lane = tid & 63, wv = tid >> 6;
    const int lr = lane & 15, lk = lane >> 4;

    #pragma unroll 1
    for (int st = 0; st < 4; ++st) {
        // ---- v1 build: vA rows [wv*16, wv*16+16) = bf16(m1 .* W1 cols) — wave-private ----
        {
            const int row = wv * 16 + (lane >> 2), kq = lane & 3;
            const int vs = (lane >> 4), vc = (lane >> 2) & 3;
            const unsigned char* mrec = ml8 + (0 * 64 + st * 16 + wv * 4 + vs) * 16;
            const unsigned short* w1t = (const unsigned short*)(wsb + WSB_W1T) + vc * HIDN;
            #pragma unroll
            for (int t = 0; t < 4; ++t) {
                const int j0 = kq * 32 + t * 8;
                const short8 w = *(const short8*)(w1t + j0);
                short8 fr;
                #pragma unroll
                for (int e = 0; e < 8; ++e) {
                    const int j = j0 + e;
                    fr[e] = ((mrec[j >> 3] >> (j & 7)) & 1u) ? w[e] : (short)0;
                }
                *(short8*)(vA + row * VSTR + j0 * 2) = fr;
            }
        }

        // ---- tangent layers 2,3 (ping-pong vA -> vB -> vA; wave-private rows) ----
        tangent_layer(vA, vB, wsb + WSB_W2B, ml8 + (1 * 64 + st * 16) * 16, wv, lr, lk);
        tangent_layer(vB, vA, wsb + WSB_W3B, ml8 + (2 * 64 + st * 16) * 16, wv, lr, lk);

        // ---- Jf: D[c'][sc] = sum_j W4[c'][j] * V3[sc][j] ----
        {
            short8 a4f[4], b[4];
            #pragma unroll
            for (int ks = 0; ks < 4; ++ks) {
                a4f[ks] = *(const short8*)(wsb + WSB_W4B + lr * 272 + ks * 64 + lk * 16);
                b[ks]   = *(const short8*)(vA + (wv * 16 + lr) * VSTR + ks * 64 + lk * 16);
            }
            f32x4 c = (f32x4){0.f, 0.f, 0.f, 0.f};
            #pragma unroll
            for (int ks = 0; ks < 4; ++ks)
                c = __builtin_amdgcn_mfma_f32_16x16x32_bf16(a4f[ks], b[ks], c, 0, 0, 0);
            if (lk == 0) {   // c' = r (0..3); sc = wv*16+lr -> jbuf rows wave-private
                const int sc = wv * 16 + lr;
                #pragma unroll
                for (int r = 0; r < 4; ++r)
                    jbuf[sc * 5 + r] = c[r];
            }
        }
        // wave-internal jbuf handoff: both sides are LDS ops -> "memory" clobber orders them
        asm volatile("s_waitcnt lgkmcnt(0)" ::: "memory");
        __builtin_amdgcn_sched_barrier(0);

        // ---- per-wave epilogue (lanes 0-15): samples wv*4 .. wv*4+3 of this subtile ----
        if (lk == 0) {
            const int es = lr >> 2, ea = lr & 3;
            const long sg = sg0 + st * 16 + wv * 4 + es;
            if (sg < (long)Btot) {
                const float* jb = jbuf + (wv * 16 + es * 4) * 5;
                float4 o;
                o.x = jb[ea * 5 + 0] - jb[0 * 5 + ea];
                o.y = jb[ea * 5 + 1] - jb[1 * 5 + ea];
                o.z = jb[ea * 5 + 2] - jb[2 * 5 + ea];
                o.w = jb[ea * 5 + 3] - jb[3 * 5 + ea];
                *(float4*)(out + sg * 16 + ea * 4) = o;
            }
        }
    }
}

extern "C" void kernel_launch(void* const* d_in, const int* in_sizes, int n_in,
                              void* d_out, int out_size, void* d_ws, size_t ws_size,
                              hipStream_t stream)
{
    const float* u  = (const float*)d_in[0];
    const float* W1 = (const float*)d_in[1];
    const float* b1 = (const float*)d_in[2];
    const float* W2 = (const float*)d_in[3];
    const float* b2 = (const float*)d_in[4];
    const float* W3 = (const float*)d_in[5];
    const float* b3 = (const float*)d_in[6];
    const float* W4 = (const float*)d_in[7];
    // d_in[8] = b4: unused (bias does not enter the Jacobian)
    float* out = (float*)d_out;
    unsigned char* wsb = (unsigned char*)d_ws;   // needs 210176 B

    const int B = in_sizes[0] / 4;
    hipLaunchKernelGGL(conv_w_kernel, dim3((16384 + 2048 + 512 + 255) / 256), dim3(256), 0, stream,
                       W1, W2, W3, W4, wsb);
    const int nblocks = (B + 63) / 64;
    hipLaunchKernelGGL(wnn_jac_kernel, dim3(nblocks), dim3(256), 0, stream,
                       u, W1, b1, b2, b3, wsb, out, B);
}

// Round 20
// 245.176 us; speedup vs baseline: 3.5793x; 1.3030x over previous
//
#include <hip/hip_runtime.h>

#define HIDN 128
#define VSTR 272           // LDS V-buffer row stride BYTES (17x16B -> conflict-free b128)
#define ASTR 132           // f32 activation row stride (floats)

// d_ws byte offsets. Forward weights TRANSPOSED: WT[jc][unit][4kk] f32, row
// stride 2064B (non-pow2 — R14). Per jc the 32 needed units are 512B contiguous.
#define WSB_W2T 0                    // f32 [32][128][4], rows 2064B
#define WSB_W3T 66048
#define WSB_W2B 135168               // bf16 [128] rows, stride 272B (tangent)
#define WSB_W3B 169984
#define WSB_W4B 204800               // bf16 [16] rows, stride 272B (rows 4..15 zero)
#define WSB_W1T 209152               // bf16 [4][128] contiguous
#define WSB_TOT 210176

typedef __attribute__((ext_vector_type(8))) short short8;
typedef __attribute__((ext_vector_type(4))) float f32x4;

// Paired-ib bf16 W load: 8 loads + wait in ONE self-contained asm block
// (R13-proven; multi-block register pipelines spill — R16, 3-for-3).
#define LOAD_A8(dst, b0, b1)                                                  \
    asm volatile("global_load_dwordx4 %0, %8, off\n\t"                        \
                 "global_load_dwordx4 %1, %8, off offset:64\n\t"              \
                 "global_load_dwordx4 %2, %8, off offset:128\n\t"             \
                 "global_load_dwordx4 %3, %8, off offset:192\n\t"             \
                 "global_load_dwordx4 %4, %9, off\n\t"                        \
                 "global_load_dwordx4 %5, %9, off offset:64\n\t"              \
                 "global_load_dwordx4 %6, %9, off offset:128\n\t"             \
                 "global_load_dwordx4 %7, %9, off offset:192\n\t"             \
                 "s_waitcnt vmcnt(0)"                                         \
                 : "=&v"(dst[0]), "=&v"(dst[1]), "=&v"(dst[2]), "=&v"(dst[3]),\
                   "=&v"(dst[4]), "=&v"(dst[5]), "=&v"(dst[6]), "=&v"(dst[7]) \
                 : "v"(b0), "v"(b1)                                           \
                 : "memory")

// f32 -> bf16 round-to-nearest-even
__device__ __forceinline__ unsigned short f2bf(float f) {
    unsigned b = __float_as_uint(f);
    b += 0x7FFFu + ((b >> 16) & 1u);
    return (unsigned short)(b >> 16);
}

// ---------- prelude: one-time weight repack into ws ----------
__global__ void conv_w_kernel(const float* __restrict__ W1, const float* __restrict__ W2,
                              const float* __restrict__ W3, const float* __restrict__ W4,
                              unsigned char* __restrict__ ws)
{
    const int idx = blockIdx.x * 256 + threadIdx.x;
    if (idx < 16384) {
        const int r = idx >> 7, c = idx & 127;           // unit r, k-col c
        const int jc = c >> 2, kk = c & 3;
        *(float*)(ws + WSB_W2T + jc * 2064 + r * 16 + kk * 4) = W2[idx];   // f32 verbatim
        *(float*)(ws + WSB_W3T + jc * 2064 + r * 16 + kk * 4) = W3[idx];
        *(unsigned short*)(ws + WSB_W2B + r * 272 + c * 2) = f2bf(W2[idx]);
        *(unsigned short*)(ws + WSB_W3B + r * 272 + c * 2) = f2bf(W3[idx]);
    } else if (idx < 16384 + 2048) {
        const int t = idx - 16384;
        const int r = t >> 7, c = t & 127;
        *(unsigned short*)(ws + WSB_W4B + r * 272 + c * 2) =
            (r < 4) ? f2bf(W4[r * HIDN + c]) : (unsigned short)0;
    } else if (idx < 16384 + 2048 + 512) {
        const int t = idx - 16384 - 2048;
        const int cc = t >> 7, j = t & 127;
        *(unsigned short*)(ws + WSB_W1T + cc * 256 + j * 2) = f2bf(W1[j * 4 + cc]);
    }
}

// One tangent layer, PING-PONG (src != dst; in-place corrupts — R6/R8, 2-for-2).
// Wave owns V rows [wv*16, wv*16+16) — wave-private, no barriers.
// msk = SUBTILE SAMPLE BASE [16][16]; wave offset added here via sc>>2 (R17 lesson).
__device__ __forceinline__ void tangent_layer(const unsigned char* __restrict__ src,
                                              unsigned char* __restrict__ dst,
                                              const unsigned char* __restrict__ Wb, // 272B rows
                                              const unsigned char* __restrict__ msk, // [16][16]
                                              int wv, int lr, int lk)
{
    short8 b[4];
    #pragma unroll
    for (int ks = 0; ks < 4; ++ks)
        b[ks] = *(const short8*)(src + (wv * 16 + lr) * VSTR + ks * 64 + lk * 16);

    const int sc = wv * 16 + lr;
    #pragma unroll
    for (int ip = 0; ip < 4; ++ip) {
        short8 a[8];
        LOAD_A8(a, Wb + ((ip * 2 + 0) * 16 + lr) * 272 + lk * 16,
                   Wb + ((ip * 2 + 1) * 16 + lr) * 272 + lk * 16);
        #pragma unroll
        for (int h = 0; h < 2; ++h) {
            const int ib = ip * 2 + h;
            f32x4 c = (f32x4){0.f, 0.f, 0.f, 0.f};
            #pragma unroll
            for (int ks = 0; ks < 4; ++ks)
                c = __builtin_amdgcn_mfma_f32_16x16x32_bf16(a[h * 4 + ks], b[ks], c, 0, 0, 0);
            const unsigned bits = (msk[(sc >> 2) * 16 + ib * 2 + (lk >> 1)] >> ((lk & 1) * 4)) & 0xFu;
            unsigned long long pk = 0;
            #pragma unroll
            for (int r = 0; r < 4; ++r) {
                const unsigned short v = ((bits >> r) & 1u) ? f2bf(c[r]) : (unsigned short)0;
                pk |= (unsigned long long)v << (r * 16);
            }
            *(unsigned long long*)(dst + sc * VSTR + ib * 32 + lk * 8) = pk;
        }
    }
}

__global__ __launch_bounds__(256, 4)
void wnn_jac_kernel(const float* __restrict__ u,
                    const float* __restrict__ W1, const float* __restrict__ b1,
                    const float* __restrict__ b2, const float* __restrict__ b3,
                    const unsigned char* __restrict__ wsb,
                    float* __restrict__ out, int Btot)
{
    // [0,17408) vA ; [17408,34816) vB ; forward aliases [0,33792) as f32 abuf[64][132]
    __shared__ __align__(16) unsigned char smem[34816];
    __shared__ unsigned char mlds8[3][64][16];   // [layer][sample][unit>>3] (3072 B)
    __shared__ float jbuf[64 * 5];               // [sc][c'] stride 5 (1280 B)

    unsigned char* vA = smem;
    unsigned char* vB = smem + 17408;
    float* abuf = (float*)smem;

    const int tid  = threadIdx.x;
    const long sg0 = (long)blockIdx.x * 64;

    // ================== FORWARD: lane = sample, wave = unit-quarter (uniform W) ==================
    {
        const int ls = tid & 63;                                   // sample
        const int wq = __builtin_amdgcn_readfirstlane(tid >> 6);   // uniform quarter 0..3
        const int i0 = wq * 32;
        const bool valid = (sg0 + ls < (long)Btot);

        float4 uv = make_float4(0.f, 0.f, 0.f, 0.f);
        if (valid) uv = *(const float4*)(u + (sg0 + ls) * 4);

        // ---- layer 1: 32 units/wave (uniform W1 rows), bit-exact chain, bias after ----
        {
            unsigned m = 0;
            #pragma unroll
            for (int ii = 0; ii < 32; ++ii) {
                const int i = i0 + ii;
                const float4 w = *(const float4*)(W1 + i * 4);     // uniform
                float h = 0.f;
                h = fmaf(w.x, uv.x, h);
                h = fmaf(w.y, uv.y, h);
                h = fmaf(w.z, uv.z, h);
                h = fmaf(w.w, uv.w, h);
                h = h + b1[i];
                if (h > 0.f) m |= (1u << ii);
                abuf[ls * ASTR + i] = fmaxf(h, 0.f);
            }
            *(unsigned*)&mlds8[0][ls][wq * 4] = m;
        }
        __syncthreads();   // B1: a1 complete

        // ---- layer 2: jc-OUTER / all-32-units-INNER (R20 change).
        //      Per jc: one ds_read_b128 (av) + one contiguous 512B uniform W run
        //      (8 cache lines, fully used, scalar path) + 128 FMA. Per-unit chain
        //      stays jc-ascending x/y/z/w from 0, bias after -> bit-exact masks.
        float acc2[32];
        {
            #pragma unroll
            for (int ii = 0; ii < 32; ++ii) acc2[ii] = 0.f;
            #pragma unroll 8
            for (int jc = 0; jc < 32; ++jc) {
                const f32x4 av = *(const f32x4*)(abuf + ls * ASTR + jc * 4);
                const float* wt = (const float*)(wsb + WSB_W2T + jc * 2064 + i0 * 16); // uniform 512B
                #pragma unroll
                for (int ii = 0; ii < 32; ++ii) {
                    const float* wr = wt + ii * 4;
                    float a = acc2[ii];
                    a = fmaf(wr[0], av[0], a);
                    a = fmaf(wr[1], av[1], a);
                    a = fmaf(wr[2], av[2], a);
                    a = fmaf(wr[3], av[3], a);
                    acc2[ii] = a;
                }
            }
        }
        __syncthreads();   // B2: ALL a1 reads complete -> safe to overwrite abuf with a2
        {
            unsigned m = 0;
            #pragma unroll
            for (int ii = 0; ii < 32; ++ii) {
                const float h = acc2[ii] + b2[i0 + ii];
                if (h > 0.f) m |= (1u << ii);
                abuf[ls * ASTR + i0 + ii] = fmaxf(h, 0.f);
            }
            *(unsigned*)&mlds8[1][ls][wq * 4] = m;
        }
        __syncthreads();   // B3: a2 complete

        // ---- layer 3 (mask only), same jc-outer structure ----
        {
            #pragma unroll
            for (int ii = 0; ii < 32; ++ii) acc2[ii] = 0.f;
            #pragma unroll 8
            for (int jc = 0; jc < 32; ++jc) {
                const f32x4 av = *(const f32x4*)(abuf + ls * ASTR + jc * 4);
                const float* wt = (const float*)(wsb + WSB_W3T + jc * 2064 + i0 * 16); // uniform 512B
                #pragma unroll
                for (int ii = 0; ii < 32; ++ii) {
                    const float* wr = wt + ii * 4;
                    float a = acc2[ii];
                    a = fmaf(wr[0], av[0], a);
                    a = fmaf(wr[1], av[1], a);
                    a = fmaf(wr[2], av[2], a);
                    a = fmaf(wr[3], av[3], a);
                    acc2[ii] = a;
                }
            }
            unsigned m = 0;
            #pragma unroll
            for (int ii = 0; ii < 32; ++ii) {
                const float h = acc2[ii] + b3[i0 + ii];
                if (h > 0.f) m |= (1u << ii);
            }
            *(unsigned*)&mlds8[2][ls][wq * 4] = m;
        }
    }
    __syncthreads();   // B4 — the ONLY barrier before the tangent phase.

    // ================== TANGENT: 4 subtiles, ZERO barriers (wave-private rows) ==================
    const unsigned char* ml8 = &mlds8[0][0][0];
    const int lane = tid & 63, wv = tid >> 6;
    const int lr = lane & 15, lk = lane >> 4;

    #pragma unroll 1
    for (int st = 0; st < 4; ++st) {
        // ---- v1 build: vA rows [wv*16, wv*16+16) = bf16(m1 .* W1 cols) — wave-private ----
        {
            const int row = wv * 16 + (lane >> 2), kq = lane & 3;
            const int vs = (lane >> 4), vc = (lane >> 2) & 3;
            const unsigned char* mrec = ml8 + (0 * 64 + st * 16 + wv * 4 + vs) * 16;
            const unsigned short* w1t = (const unsigned short*)(wsb + WSB_W1T) + vc * HIDN;
            #pragma unroll
            for (int t = 0; t < 4; ++t) {
                const int j0 = kq * 32 + t * 8;
                const short8 w = *(const short8*)(w1t + j0);
                short8 fr;
                #pragma unroll
                for (int e = 0; e < 8; ++e) {
                    const int j = j0 + e;
                    fr[e] = ((mrec[j >> 3] >> (j & 7)) & 1u) ? w[e] : (short)0;
                }
                *(short8*)(vA + row * VSTR + j0 * 2) = fr;
            }
        }

        // ---- tangent layers 2,3 (ping-pong vA -> vB -> vA; wave-private rows) ----
        tangent_layer(vA, vB, wsb + WSB_W2B, ml8 + (1 * 64 + st * 16) * 16, wv, lr, lk);
        tangent_layer(vB, vA, wsb + WSB_W3B, ml8 + (2 * 64 + st * 16) * 16, wv, lr, lk);

        // ---- Jf: D[c'][sc] = sum_j W4[c'][j] * V3[sc][j] ----
        {
            short8 a4f[4], b[4];
            #pragma unroll
            for (int ks = 0; ks < 4; ++ks) {
                a4f[ks] = *(const short8*)(wsb + WSB_W4B + lr * 272 + ks * 64 + lk * 16);
                b[ks]   = *(const short8*)(vA + (wv * 16 + lr) * VSTR + ks * 64 + lk * 16);
            }
            f32x4 c = (f32x4){0.f, 0.f, 0.f, 0.f};
            #pragma unroll
            for (int ks = 0; ks < 4; ++ks)
                c = __builtin_amdgcn_mfma_f32_16x16x32_bf16(a4f[ks], b[ks], c, 0, 0, 0);
            if (lk == 0) {   // c' = r (0..3); sc = wv*16+lr -> jbuf rows wave-private
                const int sc = wv * 16 + lr;
                #pragma unroll
                for (int r = 0; r < 4; ++r)
                    jbuf[sc * 5 + r] = c[r];
            }
        }
        // wave-internal jbuf handoff: both sides are LDS ops -> "memory" clobber orders them
        asm volatile("s_waitcnt lgkmcnt(0)" ::: "memory");
        __builtin_amdgcn_sched_barrier(0);

        // ---- per-wave epilogue (lanes 0-15): samples wv*4 .. wv*4+3 of this subtile ----
        if (lk == 0) {
            const int es = lr >> 2, ea = lr & 3;
            const long sg = sg0 + st * 16 + wv * 4 + es;
            if (sg < (long)Btot) {
                const float* jb = jbuf + (wv * 16 + es * 4) * 5;
                float4 o;
                o.x = jb[ea * 5 + 0] - jb[0 * 5 + ea];
                o.y = jb[ea * 5 + 1] - jb[1 * 5 + ea];
                o.z = jb[ea * 5 + 2] - jb[2 * 5 + ea];
                o.w = jb[ea * 5 + 3] - jb[3 * 5 + ea];
                *(float4*)(out + sg * 16 + ea * 4) = o;
            }
        }
    }
}

extern "C" void kernel_launch(void* const* d_in, const int* in_sizes, int n_in,
                              void* d_out, int out_size, void* d_ws, size_t ws_size,
                              hipStream_t stream)
{
    const float* u  = (const float*)d_in[0];
    const float* W1 = (const float*)d_in[1];
    const float* b1 = (const float*)d_in[2];
    const float* W2 = (const float*)d_in[3];
    const float* b2 = (const float*)d_in[4];
    const float* W3 = (const float*)d_in[5];
    const float* b3 = (const float*)d_in[6];
    const float* W4 = (const float*)d_in[7];
    // d_in[8] = b4: unused (bias does not enter the Jacobian)
    float* out = (float*)d_out;
    unsigned char* wsb = (unsigned char*)d_ws;   // needs 210176 B

    const int B = in_sizes[0] / 4;
    hipLaunchKernelGGL(conv_w_kernel, dim3((16384 + 2048 + 512 + 255) / 256), dim3(256), 0, stream,
                       W1, W2, W3, W4, wsb);
    const int nblocks = (B + 63) / 64;
    hipLaunchKernelGGL(wnn_jac_kernel, dim3(nblocks), dim3(256), 0, stream,
                       u, W1, b1, b2, b3, wsb, out, B);
}

// Round 21
// 213.093 us; speedup vs baseline: 4.1181x; 1.1506x over previous
//
#include <hip/hip_runtime.h>

#define HIDN 128
#define VSTR 272           // LDS V-buffer row stride BYTES (17x16B -> conflict-free b128)
#define ASTR 132           // f32 activation row stride (floats)

// d_ws byte offsets. Forward weights TRANSPOSED: WT[jc][unit][4kk] f32, row
// stride 2064B (non-pow2 — R14). Per jc the 32 needed units are 512B contiguous.
#define WSB_W2T 0                    // f32 [32][128][4], rows 2064B
#define WSB_W3T 66048
#define WSB_W2B 135168               // bf16 [128] rows, stride 272B (tangent)
#define WSB_W3B 169984
#define WSB_W4B 204800               // bf16 [16] rows, stride 272B (rows 4..15 zero)
#define WSB_W1T 209152               // bf16 [4][128] contiguous
#define WSB_TOT 210176

typedef __attribute__((ext_vector_type(8))) short short8;
typedef __attribute__((ext_vector_type(4))) float f32x4;

// Paired-row bf16 W load: 8 loads + wait in ONE self-contained asm block
// (R13-proven; multi-block register pipelines spill — R16, 3-for-3).
#define LOAD_A8(dst, b0, b1)                                                  \
    asm volatile("global_load_dwordx4 %0, %8, off\n\t"                        \
                 "global_load_dwordx4 %1, %8, off offset:64\n\t"              \
                 "global_load_dwordx4 %2, %8, off offset:128\n\t"             \
                 "global_load_dwordx4 %3, %8, off offset:192\n\t"             \
                 "global_load_dwordx4 %4, %9, off\n\t"                        \
                 "global_load_dwordx4 %5, %9, off offset:64\n\t"              \
                 "global_load_dwordx4 %6, %9, off offset:128\n\t"             \
                 "global_load_dwordx4 %7, %9, off offset:192\n\t"             \
                 "s_waitcnt vmcnt(0)"                                         \
                 : "=&v"(dst[0]), "=&v"(dst[1]), "=&v"(dst[2]), "=&v"(dst[3]),\
                   "=&v"(dst[4]), "=&v"(dst[5]), "=&v"(dst[6]), "=&v"(dst[7]) \
                 : "v"(b0), "v"(b1)                                           \
                 : "memory")

// f32 -> bf16 round-to-nearest-even
__device__ __forceinline__ unsigned short f2bf(float f) {
    unsigned b = __float_as_uint(f);
    b += 0x7FFFu + ((b >> 16) & 1u);
    return (unsigned short)(b >> 16);
}

// ---------- prelude: one-time weight repack into ws ----------
__global__ void conv_w_kernel(const float* __restrict__ W1, const float* __restrict__ W2,
                              const float* __restrict__ W3, const float* __restrict__ W4,
                              unsigned char* __restrict__ ws)
{
    const int idx = blockIdx.x * 256 + threadIdx.x;
    if (idx < 16384) {
        const int r = idx >> 7, c = idx & 127;           // unit r, k-col c
        const int jc = c >> 2, kk = c & 3;
        *(float*)(ws + WSB_W2T + jc * 2064 + r * 16 + kk * 4) = W2[idx];   // f32 verbatim
        *(float*)(ws + WSB_W3T + jc * 2064 + r * 16 + kk * 4) = W3[idx];
        *(unsigned short*)(ws + WSB_W2B + r * 272 + c * 2) = f2bf(W2[idx]);
        *(unsigned short*)(ws + WSB_W3B + r * 272 + c * 2) = f2bf(W3[idx]);
    } else if (idx < 16384 + 2048) {
        const int t = idx - 16384;
        const int r = t >> 7, c = t & 127;
        *(unsigned short*)(ws + WSB_W4B + r * 272 + c * 2) =
            (r < 4) ? f2bf(W4[r * HIDN + c]) : (unsigned short)0;
    } else if (idx < 16384 + 2048 + 512) {
        const int t = idx - 16384 - 2048;
        const int cc = t >> 7, j = t & 127;
        *(unsigned short*)(ws + WSB_W1T + cc * 256 + j * 2) = f2bf(W1[j * 4 + cc]);
    }
}

// One tangent layer, WIDE split (R21): wave owns UNITS [ub, ub+32) for ALL 64
// sc-rows. W fragments for this wave = ONE LOAD_A8 (1 round-trip vs 4).
// PING-PONG src != dst (in-place corrupts — R6/R8). Writes to shared rows are
// byte-disjoint per wave (unit-column ranges); caller provides barriers.
// msk = SUBTILE SAMPLE BASE [16][16].
__device__ __forceinline__ void tangent_layer_wide(const unsigned char* __restrict__ src,
                                                   unsigned char* __restrict__ dst,
                                                   const unsigned char* __restrict__ Wb,  // 272B rows
                                                   const unsigned char* __restrict__ msk, // [16][16]
                                                   int ub, int lr, int lk)
{
    short8 aw[8];   // 2 ib-blocks x 4 k-slices
    LOAD_A8(aw, Wb + (ub + lr) * 272 + lk * 16,
                Wb + (ub + 16 + lr) * 272 + lk * 16);
    const int ib0 = ub >> 4;
    #pragma unroll
    for (int q = 0; q < 4; ++q) {
        const int sc = q * 16 + lr;
        short8 b[4];
        #pragma unroll
        for (int ks = 0; ks < 4; ++ks)
            b[ks] = *(const short8*)(src + sc * VSTR + ks * 64 + lk * 16);
        #pragma unroll
        for (int h = 0; h < 2; ++h) {
            const int ib = ib0 + h;
            f32x4 c = (f32x4){0.f, 0.f, 0.f, 0.f};
            #pragma unroll
            for (int ks = 0; ks < 4; ++ks)
                c = __builtin_amdgcn_mfma_f32_16x16x32_bf16(aw[h * 4 + ks], b[ks], c, 0, 0, 0);
            const unsigned bits = (msk[(sc >> 2) * 16 + ib * 2 + (lk >> 1)] >> ((lk & 1) * 4)) & 0xFu;
            unsigned long long pk = 0;
            #pragma unroll
            for (int r = 0; r < 4; ++r) {
                const unsigned short v = ((bits >> r) & 1u) ? f2bf(c[r]) : (unsigned short)0;
                pk |= (unsigned long long)v << (r * 16);
            }
            *(unsigned long long*)(dst + sc * VSTR + (ib * 16 + lk * 4) * 2) = pk;
        }
    }
}

__global__ __launch_bounds__(256, 4)
void wnn_jac_kernel(const float* __restrict__ u,
                    const float* __restrict__ W1, const float* __restrict__ b1,
                    const float* __restrict__ b2, const float* __restrict__ b3,
                    const unsigned char* __restrict__ wsb,
                    float* __restrict__ out, int Btot)
{
    // [0,17408) vA ; [17408,34816) vB ; forward aliases [0,33792) as f32 abuf[64][132]
    __shared__ __align__(16) unsigned char smem[34816];
    __shared__ unsigned char mlds8[3][64][16];   // [layer][sample][unit>>3] (3072 B)
    __shared__ float jbuf[64 * 5];               // [sc][c'] stride 5 (1280 B)

    unsigned char* vA = smem;
    unsigned char* vB = smem + 17408;
    float* abuf = (float*)smem;

    const int tid  = threadIdx.x;
    const long sg0 = (long)blockIdx.x * 64;

    // ================== FORWARD: lane = sample, wave = unit-quarter (uniform W) — R20 verbatim ==================
    {
        const int ls = tid & 63;                                   // sample
        const int wq = __builtin_amdgcn_readfirstlane(tid >> 6);   // uniform quarter 0..3
        const int i0 = wq * 32;
        const bool valid = (sg0 + ls < (long)Btot);

        float4 uv = make_float4(0.f, 0.f, 0.f, 0.f);
        if (valid) uv = *(const float4*)(u + (sg0 + ls) * 4);

        // ---- layer 1: 32 units/wave (uniform W1 rows), bit-exact chain, bias after ----
        {
            unsigned m = 0;
            #pragma unroll
            for (int ii = 0; ii < 32; ++ii) {
                const int i = i0 + ii;
                const float4 w = *(const float4*)(W1 + i * 4);     // uniform
                float h = 0.f;
                h = fmaf(w.x, uv.x, h);
                h = fmaf(w.y, uv.y, h);
                h = fmaf(w.z, uv.z, h);
                h = fmaf(w.w, uv.w, h);
                h = h + b1[i];
                if (h > 0.f) m |= (1u << ii);
                abuf[ls * ASTR + i] = fmaxf(h, 0.f);
            }
            *(unsigned*)&mlds8[0][ls][wq * 4] = m;
        }
        __syncthreads();   // B1: a1 complete

        // ---- layer 2: jc-OUTER / all-32-units-INNER (R20-proven) ----
        float acc2[32];
        {
            #pragma unroll
            for (int ii = 0; ii < 32; ++ii) acc2[ii] = 0.f;
            #pragma unroll 8
            for (int jc = 0; jc < 32; ++jc) {
                const f32x4 av = *(const f32x4*)(abuf + ls * ASTR + jc * 4);
                const float* wt = (const float*)(wsb + WSB_W2T + jc * 2064 + i0 * 16); // uniform 512B
                #pragma unroll
                for (int ii = 0; ii < 32; ++ii) {
                    const float* wr = wt + ii * 4;
                    float a = acc2[ii];
                    a = fmaf(wr[0], av[0], a);
                    a = fmaf(wr[1], av[1], a);
                    a = fmaf(wr[2], av[2], a);
                    a = fmaf(wr[3], av[3], a);
                    acc2[ii] = a;
                }
            }
        }
        __syncthreads();   // B2: ALL a1 reads complete -> safe to overwrite abuf with a2
        {
            unsigned m = 0;
            #pragma unroll
            for (int ii = 0; ii < 32; ++ii) {
                const float h = acc2[ii] + b2[i0 + ii];
                if (h > 0.f) m |= (1u << ii);
                abuf[ls * ASTR + i0 + ii] = fmaxf(h, 0.f);
            }
            *(unsigned*)&mlds8[1][ls][wq * 4] = m;
        }
        __syncthreads();   // B3: a2 complete

        // ---- layer 3 (mask only), same jc-outer structure ----
        {
            #pragma unroll
            for (int ii = 0; ii < 32; ++ii) acc2[ii] = 0.f;
            #pragma unroll 8
            for (int jc = 0; jc < 32; ++jc) {
                const f32x4 av = *(const f32x4*)(abuf + ls * ASTR + jc * 4);
                const float* wt = (const float*)(wsb + WSB_W3T + jc * 2064 + i0 * 16); // uniform 512B
                #pragma unroll
                for (int ii = 0; ii < 32; ++ii) {
                    const float* wr = wt + ii * 4;
                    float a = acc2[ii];
                    a = fmaf(wr[0], av[0], a);
                    a = fmaf(wr[1], av[1], a);
                    a = fmaf(wr[2], av[2], a);
                    a = fmaf(wr[3], av[3], a);
                    acc2[ii] = a;
                }
            }
            unsigned m = 0;
            #pragma unroll
            for (int ii = 0; ii < 32; ++ii) {
                const float h = acc2[ii] + b3[i0 + ii];
                if (h > 0.f) m |= (1u << ii);
            }
            *(unsigned*)&mlds8[2][ls][wq * 4] = m;
        }
    }
    __syncthreads();   // B4: masks visible; abuf dead -> vA/vB reusable

    // ================== TANGENT: 4 subtiles, wide unit-split (R21) ==================
    const unsigned char* ml8 = &mlds8[0][0][0];
    const int lane = tid & 63, wv = tid >> 6;
    const int lr = lane & 15, lk = lane >> 4;
    const int ub = wv * 32;    // this wave's unit base for tangent layers

    // W4 fragments are subtile-invariant: load ONCE (saves 3 round-trips).
    short8 a4f[4];
    #pragma unroll
    for (int ks = 0; ks < 4; ++ks)
        a4f[ks] = *(const short8*)(wsb + WSB_W4B + lr * 272 + ks * 64 + lk * 16);

    #pragma unroll 1
    for (int st = 0; st < 4; ++st) {
        __syncthreads();   // prev subtile's vA readers (Jf/L3 writers) done -> v1 may overwrite

        // ---- v1 build: vA rows [wv*16, wv*16+16) = bf16(m1 .* W1 cols) ----
        {
            const int row = wv * 16 + (lane >> 2), kq = lane & 3;
            const int vs = (lane >> 4), vc = (lane >> 2) & 3;
            const unsigned char* mrec = ml8 + (0 * 64 + st * 16 + wv * 4 + vs) * 16;
            const unsigned short* w1t = (const unsigned short*)(wsb + WSB_W1T) + vc * HIDN;
            #pragma unroll
            for (int t = 0; t < 4; ++t) {
                const int j0 = kq * 32 + t * 8;
                const short8 w = *(const short8*)(w1t + j0);
                short8 fr;
                #pragma unroll
                for (int e = 0; e < 8; ++e) {
                    const int j = j0 + e;
                    fr[e] = ((mrec[j >> 3] >> (j & 7)) & 1u) ? w[e] : (short)0;
                }
                *(short8*)(vA + row * VSTR + j0 * 2) = fr;
            }
        }
        __syncthreads();   // all vA rows ready (L2 reads every row)

        // ---- tangent L2: vA -> vB (wave computes its 32 units for all 64 rows) ----
        tangent_layer_wide(vA, vB, wsb + WSB_W2B, ml8 + (1 * 64 + st * 16) * 16, ub, lr, lk);
        __syncthreads();   // all vB writes visible

        // ---- tangent L3: vB -> vA ----
        tangent_layer_wide(vB, vA, wsb + WSB_W3B, ml8 + (2 * 64 + st * 16) * 16, ub, lr, lk);
        __syncthreads();   // all vA writes visible (Jf reads full rows)

        // ---- Jf: D[c'][sc] = sum_j W4[c'][j] * V3[sc][j] (own wave's 16 rows) ----
        {
            short8 b[4];
            #pragma unroll
            for (int ks = 0; ks < 4; ++ks)
                b[ks] = *(const short8*)(vA + (wv * 16 + lr) * VSTR + ks * 64 + lk * 16);
            f32x4 c = (f32x4){0.f, 0.f, 0.f, 0.f};
            #pragma unroll
            for (int ks = 0; ks < 4; ++ks)
                c = __builtin_amdgcn_mfma_f32_16x16x32_bf16(a4f[ks], b[ks], c, 0, 0, 0);
            if (lk == 0) {   // c' = r (0..3); sc = wv*16+lr -> jbuf rows wave-private
                const int sc = wv * 16 + lr;
                #pragma unroll
                for (int r = 0; r < 4; ++r)
                    jbuf[sc * 5 + r] = c[r];
            }
        }
        // wave-internal jbuf handoff: both sides are LDS ops -> "memory" clobber orders them
        asm volatile("s_waitcnt lgkmcnt(0)" ::: "memory");
        __builtin_amdgcn_sched_barrier(0);

        // ---- per-wave epilogue (lanes 0-15): samples wv*4 .. wv*4+3 of this subtile ----
        if (lk == 0) {
            const int es = lr >> 2, ea = lr & 3;
            const long sg = sg0 + st * 16 + wv * 4 + es;
            if (sg < (long)Btot) {
                const float* jb = jbuf + (wv * 16 + es * 4) * 5;
                float4 o;
                o.x = jb[ea * 5 + 0] - jb[0 * 5 + ea];
                o.y = jb[ea * 5 + 1] - jb[1 * 5 + ea];
                o.z = jb[ea * 5 + 2] - jb[2 * 5 + ea];
                o.w = jb[ea * 5 + 3] - jb[3 * 5 + ea];
                *(float4*)(out + sg * 16 + ea * 4) = o;
            }
        }
    }
}

extern "C" void kernel_launch(void* const* d_in, const int* in_sizes, int n_in,
                              void* d_out, int out_size, void* d_ws, size_t ws_size,
                              hipStream_t stream)
{
    const float* u  = (const float*)d_in[0];
    const float* W1 = (const float*)d_in[1];
    const float* b1 = (const float*)d_in[2];
    const float* W2 = (const float*)d_in[3];
    const float* b2 = (const float*)d_in[4];
    const float* W3 = (const float*)d_in[5];
    const float* b3 = (const float*)d_in[6];
    const float* W4 = (const float*)d_in[7];
    // d_in[8] = b4: unused (bias does not enter the Jacobian)
    float* out = (float*)d_out;
    unsigned char* wsb = (unsigned char*)d_ws;   // needs 210176 B

    const int B = in_sizes[0] / 4;
    hipLaunchKernelGGL(conv_w_kernel, dim3((16384 + 2048 + 512 + 255) / 256), dim3(256), 0, stream,
                       W1, W2, W3, W4, wsb);
    const int nblocks = (B + 63) / 64;
    hipLaunchKernelGGL(wnn_jac_kernel, dim3(nblocks), dim3(256), 0, stream,
                       u, W1, b1, b2, b3, wsb, out, B);
}